// Round 1
// baseline (421.788 us; speedup 1.0000x reference)
//
#include <hip/hip_runtime.h>
#include <math.h>

// FourierCrossAttention forward, fp32 throughout.
// B=32 L=1024 H=8 E=64 HE=512 M=64 O=64
#define TWO_PI_F 6.28318530717958647692f

// workspace layout (float offsets). Total 12M floats = 48 MB.
static constexpr size_t XQR_ = 0;         // [B][M][HE] q-spectrum real
static constexpr size_t XQI_ = 1048576;
static constexpr size_t XKR_ = 2097152;   // [B][M][HE] k-spectrum
static constexpr size_t XKI_ = 3145728;
static constexpr size_t TR_  = 4194304;   // [B][H][Mq][Mkv] tanh(QK)
static constexpr size_t TI_  = 5242880;
static constexpr size_t VR_  = 6291456;   // [B][H][Mq=x][E] xqkv (x-major!)
static constexpr size_t VI_  = 7340032;
static constexpr size_t WTR_ = 8388608;   // [H][x][E][O] transposed weights (2M floats)
static constexpr size_t WTI_ = 10485760;
static constexpr size_t UR_  = XQR_;      // [B][H][M][O] xqkvw — reuses XQ (dead after k2)
static constexpr size_t UI_  = XQI_;

__device__ __forceinline__ float f4c(const float4 v, int i) {
  return (i == 0) ? v.x : (i == 1) ? v.y : (i == 2) ? v.z : v.w;
}

// acc += (sr + i·si) * (br + i·bi), 4 lanes
__device__ __forceinline__ void cmac4(float4& ar, float4& ai, float sr, float si,
                                      const float4 br, const float4 bi) {
  ar.x += sr * br.x - si * bi.x;  ai.x += sr * bi.x + si * br.x;
  ar.y += sr * br.y - si * bi.y;  ai.y += sr * bi.y + si * br.y;
  ar.z += sr * br.z - si * bi.z;  ai.z += sr * bi.z + si * br.z;
  ar.w += sr * br.w - si * bi.w;  ai.w += sr * bi.w + si * br.w;
}

#define DMAC4(AR, AI, Q) \
  AR.x += Q.x * cc; AI.x -= Q.x * ss; \
  AR.y += Q.y * cc; AI.y -= Q.y * ss; \
  AR.z += Q.z * cc; AI.z -= Q.z * ss; \
  AR.w += Q.w * cc; AI.w -= Q.w * ss;

#define RMAC4(A, UR, UI) \
  A.x += cc * UR.x - ss * UI.x; \
  A.y += cc * UR.y - ss * UI.y; \
  A.z += cc * UR.z - ss * UI.z; \
  A.w += cc * UR.w - ss * UI.w;

// ---------------- kernel T: W[h][e][o][x] -> Wt[h][x][e][o] -------------
__global__ __launch_bounds__(256) void wtrans_kernel(const float* __restrict__ Wr,
                                                     const float* __restrict__ Wi,
                                                     float* __restrict__ ws) {
  float* Wtr = ws + WTR_;
  float* Wti = ws + WTI_;
  const int h = blockIdx.x >> 6;
  const int tile = blockIdx.x & 63;   // eo tile of 64
  const int t = threadIdx.x;
  __shared__ float lr[64][68], li_[64][68];
  const size_t rbase = (size_t)h * 262144 + (size_t)tile * 64 * 64;
#pragma unroll
  for (int i = 0; i < 4; ++i) {
    int idx = t + i * 256;
    int r = idx >> 4, x4 = idx & 15;
    float4 a = *(const float4*)(Wr + rbase + (size_t)r * 64 + x4 * 4);
    float4 b = *(const float4*)(Wi + rbase + (size_t)r * 64 + x4 * 4);
    *(float4*)(&lr[r][x4 * 4]) = a;
    *(float4*)(&li_[r][x4 * 4]) = b;
  }
  __syncthreads();
  const size_t wbase = (size_t)h * 262144 + (size_t)tile * 64;
#pragma unroll
  for (int i = 0; i < 4; ++i) {
    int idx = t + i * 256;
    int x = idx >> 4, r4 = idx & 15;
    float4 a, b;
    a.x = lr[r4 * 4 + 0][x]; a.y = lr[r4 * 4 + 1][x];
    a.z = lr[r4 * 4 + 2][x]; a.w = lr[r4 * 4 + 3][x];
    b.x = li_[r4 * 4 + 0][x]; b.y = li_[r4 * 4 + 1][x];
    b.z = li_[r4 * 4 + 2][x]; b.w = li_[r4 * 4 + 3][x];
    *(float4*)(Wtr + wbase + (size_t)x * 4096 + r4 * 4) = a;
    *(float4*)(Wti + wbase + (size_t)x * 4096 + r4 * 4) = b;
  }
}

// ---------------- kernel 1: 64-mode DFT of q and k ----------------------
// grid 512: tz(2) x b(32) x het(8). block 256: m = t&63, heg = t>>6 (16 he each)
__global__ __launch_bounds__(256) void dft_kernel(const float* __restrict__ q,
                                                  const float* __restrict__ k,
                                                  float* __restrict__ ws) {
  const int bi = blockIdx.x;
  const int tz = bi >> 8;
  const int b = (bi & 255) >> 3;
  const int het = bi & 7;
  const float* src = tz ? k : q;
  float* dstR = ws + (tz ? XKR_ : XQR_);
  float* dstI = ws + (tz ? XKI_ : XQI_);
  const int t = threadIdx.x;
  const int m = t & 63;
  const int heBase = (t >> 6) * 16;

  __shared__ float tile[64][64];   // [li][he] 16 KB

  float4 aR0 = {0,0,0,0}, aR1 = {0,0,0,0}, aR2 = {0,0,0,0}, aR3 = {0,0,0,0};
  float4 aI0 = {0,0,0,0}, aI1 = {0,0,0,0}, aI2 = {0,0,0,0}, aI3 = {0,0,0,0};
  float cd, sd;
  sincosf((float)m * (TWO_PI_F / 1024.0f), &sd, &cd);   // per-l rotation step

  const float* srcB = src + (size_t)b * 524288 + het * 64;
  for (int c = 0; c < 16; ++c) {
    const int l0 = c * 64;
    __syncthreads();
#pragma unroll
    for (int i = 0; i < 4; ++i) {
      int idx = t + i * 256;
      int li = idx >> 4, h4 = idx & 15;
      *(float4*)(&tile[li][h4 * 4]) =
          *(const float4*)(srcB + (size_t)(l0 + li) * 512 + h4 * 4);
    }
    __syncthreads();
    // re-seed twiddle at l0 (bounds rotation drift to ~1e-5)
    int p0 = (m * l0) & 1023;
    float cc, ss;
    sincosf((float)p0 * (TWO_PI_F / 1024.0f), &ss, &cc);
#pragma unroll 4
    for (int li = 0; li < 64; ++li) {
      const float4* tr = (const float4*)(&tile[li][heBase]);  // broadcast b128
      float4 q0 = tr[0], q1 = tr[1], q2 = tr[2], q3 = tr[3];
      DMAC4(aR0, aI0, q0)
      DMAC4(aR1, aI1, q1)
      DMAC4(aR2, aI2, q2)
      DMAC4(aR3, aI3, q3)
      float nc = cc * cd - ss * sd;
      ss = cc * sd + ss * cd;
      cc = nc;
    }
  }
  float* oR = dstR + (size_t)b * 32768 + (size_t)m * 512 + het * 64 + heBase;
  float* oI = dstI + (size_t)b * 32768 + (size_t)m * 512 + het * 64 + heBase;
  ((float4*)oR)[0] = aR0; ((float4*)oR)[1] = aR1;
  ((float4*)oR)[2] = aR2; ((float4*)oR)[3] = aR3;
  ((float4*)oI)[0] = aI0; ((float4*)oI)[1] = aI1;
  ((float4*)oI)[2] = aI2; ((float4*)oI)[3] = aI3;
}

// ---------------- complex tanh --------------------------------------
// tanh(a+ib) = (sinh2a + i sin2b) / (cosh2a + cos2b)
__device__ __forceinline__ void ctanh1(float a, float b, float& re, float& im) {
  float aa = fabsf(a);
  if (aa > 12.0f) {            // cosh(24)=2.6e10 -> im ~ 1e-10, ref fp32 saturates too
    re = copysignf(1.0f, a);
    im = 0.0f;
    return;
  }
  float e2 = __expf(2.0f * aa);
  float ie = 1.0f / e2;
  float sh = 0.5f * (e2 - ie);
  float ch = 0.5f * (e2 + ie);
  float s2, c2;
  sincosf(2.0f * b, &s2, &c2);   // accurate path: b can be ~3e4, needs real range reduction
  float d = ch + c2;
  float id = 1.0f / d;
  re = copysignf(sh, a) * id;
  im = s2 * id;
}

__device__ __forceinline__ void ctanh4(const float4 ar, const float4 ai, float4& tr, float4& ti) {
  ctanh1(ar.x, ai.x, tr.x, ti.x);
  ctanh1(ar.y, ai.y, tr.y, ti.y);
  ctanh1(ar.z, ai.z, tr.z, ti.z);
  ctanh1(ar.w, ai.w, tr.w, ti.w);
}

// ---------------- kernel 2: T = tanh(XQ · XK^T over e) ------------------
// grid 256 (b,h). thread: x = t>>2, yg = t&3 (16 y). LDS: K transposed [e][y].
__global__ __launch_bounds__(256) void qk_tanh_kernel(float* __restrict__ ws) {
  const float* XQr = ws + XQR_;
  const float* XQi = ws + XQI_;
  const float* XKr = ws + XKR_;
  const float* XKi = ws + XKI_;
  float* Trp = ws + TR_;
  float* Tip = ws + TI_;
  const int bh = blockIdx.x;
  const int b = bh >> 3, h = bh & 7;
  const int t = threadIdx.x;
  const int x = t >> 2, yg = t & 3;
  __shared__ float Kr[64][68], Ki[64][68];    // [e][y], pad 68 keeps b128 reads aligned
#pragma unroll
  for (int i = 0; i < 4; ++i) {
    int idx = t + i * 256;
    int yl = idx >> 4, e4 = idx & 15;
    size_t g = (size_t)b * 32768 + (size_t)yl * 512 + h * 64 + e4 * 4;
    float4 vr = *(const float4*)(XKr + g);
    float4 vi = *(const float4*)(XKi + g);
    Kr[e4 * 4 + 0][yl] = vr.x; Kr[e4 * 4 + 1][yl] = vr.y;
    Kr[e4 * 4 + 2][yl] = vr.z; Kr[e4 * 4 + 3][yl] = vr.w;
    Ki[e4 * 4 + 0][yl] = vi.x; Ki[e4 * 4 + 1][yl] = vi.y;
    Ki[e4 * 4 + 2][yl] = vi.z; Ki[e4 * 4 + 3][yl] = vi.w;
  }
  __syncthreads();
  float4 aR0 = {0,0,0,0}, aR1 = {0,0,0,0}, aR2 = {0,0,0,0}, aR3 = {0,0,0,0};
  float4 aI0 = {0,0,0,0}, aI1 = {0,0,0,0}, aI2 = {0,0,0,0}, aI3 = {0,0,0,0};
  const float* qbr = XQr + (size_t)b * 32768 + (size_t)x * 512 + h * 64;
  const float* qbi = XQi + (size_t)b * 32768 + (size_t)x * 512 + h * 64;
  for (int ec = 0; ec < 4; ++ec) {
    float4 pr[4], pim[4];
    const float4* gr = (const float4*)(qbr + ec * 16);
    const float4* gi = (const float4*)(qbi + ec * 16);
    pr[0] = gr[0]; pr[1] = gr[1]; pr[2] = gr[2]; pr[3] = gr[3];
    pim[0] = gi[0]; pim[1] = gi[1]; pim[2] = gi[2]; pim[3] = gi[3];
#pragma unroll
    for (int jj = 0; jj < 16; ++jj) {
      int e = ec * 16 + jj;
      float sr = f4c(pr[jj >> 2], jj & 3);
      float si = f4c(pim[jj >> 2], jj & 3);
      const float4* br = (const float4*)(&Kr[e][yg * 16]);
      const float4* bi = (const float4*)(&Ki[e][yg * 16]);
      cmac4(aR0, aI0, sr, si, br[0], bi[0]);
      cmac4(aR1, aI1, sr, si, br[1], bi[1]);
      cmac4(aR2, aI2, sr, si, br[2], bi[2]);
      cmac4(aR3, aI3, sr, si, br[3], bi[3]);
    }
  }
  float* oR = Trp + ((size_t)bh * 64 + x) * 64 + yg * 16;
  float* oI = Tip + ((size_t)bh * 64 + x) * 64 + yg * 16;
  float4 tR, tI;
  ctanh4(aR0, aI0, tR, tI); ((float4*)oR)[0] = tR; ((float4*)oI)[0] = tI;
  ctanh4(aR1, aI1, tR, tI); ((float4*)oR)[1] = tR; ((float4*)oI)[1] = tI;
  ctanh4(aR2, aI2, tR, tI); ((float4*)oR)[2] = tR; ((float4*)oI)[2] = tI;
  ctanh4(aR3, aI3, tR, tI); ((float4*)oR)[3] = tR; ((float4*)oI)[3] = tI;
}

// ---------------- kernel 3: V[b,h,x,e] = sum_y T[x,y] * XK[e,y] ---------
// grid 256 (b,h). thread: x = t>>2, eg = t&3. LDS: XK native [y][e].
__global__ __launch_bounds__(256) void xqkv_kernel(float* __restrict__ ws) {
  const float* XKr = ws + XKR_;
  const float* XKi = ws + XKI_;
  const float* Trp = ws + TR_;
  const float* Tip = ws + TI_;
  float* Vr = ws + VR_;
  float* Vi = ws + VI_;
  const int bh = blockIdx.x;
  const int b = bh >> 3, h = bh & 7;
  const int t = threadIdx.x;
  const int x = t >> 2, eg = t & 3;
  __shared__ float Kr[64][64], Ki[64][64];   // [y][e] direct copy
#pragma unroll
  for (int i = 0; i < 4; ++i) {
    int idx = t + i * 256;
    int yl = idx >> 4, e4 = idx & 15;
    size_t g = (size_t)b * 32768 + (size_t)yl * 512 + h * 64 + e4 * 4;
    *(float4*)(&Kr[yl][e4 * 4]) = *(const float4*)(XKr + g);
    *(float4*)(&Ki[yl][e4 * 4]) = *(const float4*)(XKi + g);
  }
  __syncthreads();
  float4 aR0 = {0,0,0,0}, aR1 = {0,0,0,0}, aR2 = {0,0,0,0}, aR3 = {0,0,0,0};
  float4 aI0 = {0,0,0,0}, aI1 = {0,0,0,0}, aI2 = {0,0,0,0}, aI3 = {0,0,0,0};
  const float* tbr = Trp + ((size_t)bh * 64 + x) * 64;
  const float* tbi = Tip + ((size_t)bh * 64 + x) * 64;
  for (int yc = 0; yc < 4; ++yc) {
    float4 pr[4], pim[4];
    const float4* gr = (const float4*)(tbr + yc * 16);
    const float4* gi = (const float4*)(tbi + yc * 16);
    pr[0] = gr[0]; pr[1] = gr[1]; pr[2] = gr[2]; pr[3] = gr[3];
    pim[0] = gi[0]; pim[1] = gi[1]; pim[2] = gi[2]; pim[3] = gi[3];
#pragma unroll
    for (int jj = 0; jj < 16; ++jj) {
      int y = yc * 16 + jj;
      float sr = f4c(pr[jj >> 2], jj & 3);
      float si = f4c(pim[jj >> 2], jj & 3);
      const float4* br = (const float4*)(&Kr[y][eg * 16]);
      const float4* bi = (const float4*)(&Ki[y][eg * 16]);
      cmac4(aR0, aI0, sr, si, br[0], bi[0]);
      cmac4(aR1, aI1, sr, si, br[1], bi[1]);
      cmac4(aR2, aI2, sr, si, br[2], bi[2]);
      cmac4(aR3, aI3, sr, si, br[3], bi[3]);
    }
  }
  float* oR = Vr + ((size_t)bh * 64 + x) * 64 + eg * 16;
  float* oI = Vi + ((size_t)bh * 64 + x) * 64 + eg * 16;
  ((float4*)oR)[0] = aR0; ((float4*)oR)[1] = aR1;
  ((float4*)oR)[2] = aR2; ((float4*)oR)[3] = aR3;
  ((float4*)oI)[0] = aI0; ((float4*)oI)[1] = aI1;
  ((float4*)oI)[2] = aI2; ((float4*)oI)[3] = aI3;
}

// ---------------- kernel 4: U[b,h,x,o] = sum_e V[b,h,x,e] * Wt[h,x,e,o] --
// grid 512 (h*64+x). thread: bI = t>>3, og = t&7 (8 o).
__global__ __launch_bounds__(256) void wmul_kernel(float* __restrict__ ws) {
  const float* Vr = ws + VR_;
  const float* Vi = ws + VI_;
  float* Ur = ws + UR_;
  float* Ui = ws + UI_;
  const float* Wtr = ws + WTR_;
  const float* Wti = ws + WTI_;
  const int h = blockIdx.x >> 6, x = blockIdx.x & 63;
  const int t = threadIdx.x;
  const int bI = t >> 3, og = t & 7;
  __shared__ float Ws_r[64][64], Ws_i[64][64];   // [e][o]
  const size_t wb = ((size_t)h * 64 + x) * 4096;
#pragma unroll
  for (int i = 0; i < 4; ++i) {
    int idx = t + i * 256;
    int el = idx >> 4, o4 = idx & 15;
    *(float4*)(&Ws_r[el][o4 * 4]) = *(const float4*)(Wtr + wb + (size_t)el * 64 + o4 * 4);
    *(float4*)(&Ws_i[el][o4 * 4]) = *(const float4*)(Wti + wb + (size_t)el * 64 + o4 * 4);
  }
  __syncthreads();
  float4 aR0 = {0,0,0,0}, aR1 = {0,0,0,0}, aI0 = {0,0,0,0}, aI1 = {0,0,0,0};
  const float* vbr = Vr + (((size_t)bI * 8 + h) * 64 + x) * 64;
  const float* vbi = Vi + (((size_t)bI * 8 + h) * 64 + x) * 64;
  for (int ec = 0; ec < 4; ++ec) {
    float4 pr[4], pim[4];
    const float4* gr = (const float4*)(vbr + ec * 16);
    const float4* gi = (const float4*)(vbi + ec * 16);
    pr[0] = gr[0]; pr[1] = gr[1]; pr[2] = gr[2]; pr[3] = gr[3];
    pim[0] = gi[0]; pim[1] = gi[1]; pim[2] = gi[2]; pim[3] = gi[3];
#pragma unroll
    for (int jj = 0; jj < 16; ++jj) {
      int e = ec * 16 + jj;
      float sr = f4c(pr[jj >> 2], jj & 3);
      float si = f4c(pim[jj >> 2], jj & 3);
      const float4* br = (const float4*)(&Ws_r[e][og * 8]);
      const float4* bi = (const float4*)(&Ws_i[e][og * 8]);
      cmac4(aR0, aI0, sr, si, br[0], bi[0]);
      cmac4(aR1, aI1, sr, si, br[1], bi[1]);
    }
  }
  float* oR = Ur + (((size_t)bI * 8 + h) * 64 + x) * 64 + og * 8;
  float* oI = Ui + (((size_t)bI * 8 + h) * 64 + x) * 64 + og * 8;
  ((float4*)oR)[0] = aR0; ((float4*)oR)[1] = aR1;
  ((float4*)oI)[0] = aI0; ((float4*)oI)[1] = aI1;
}

// ---------------- kernel 5: irfft (64 modes -> 1024) --------------------
// out[b,h,o,l] = 2^-27 * (0.5*Ur[0,o] + sum_{m=1}^{63} Ur[m,o]cos(2pi m l/1024) - Ui[m,o]sin(...))
// grid 4096 = (b,h)*16 l-tiles. thread: l = lt*64 + (t&63), og = t>>6 (16 o).
__global__ __launch_bounds__(256) void idft_kernel(const float* __restrict__ ws,
                                                   float* __restrict__ out) {
  const float* Ur = ws + UR_;
  const float* Ui = ws + UI_;
  const int bh = blockIdx.x >> 4;
  const int lt = blockIdx.x & 15;
  const int t = threadIdx.x;
  const int l = lt * 64 + (t & 63);
  const int og = t >> 6;
  __shared__ float Us_r[64][64], Us_i[64][64];   // [m][o]
#pragma unroll
  for (int i = 0; i < 4; ++i) {
    int idx = t + i * 256;
    int ml = idx >> 4, o4 = idx & 15;
    size_t g = ((size_t)bh * 64 + ml) * 64 + o4 * 4;
    *(float4*)(&Us_r[ml][o4 * 4]) = *(const float4*)(Ur + g);
    *(float4*)(&Us_i[ml][o4 * 4]) = *(const float4*)(Ui + g);
  }
  __syncthreads();
  const float4* u0 = (const float4*)(&Us_r[0][og * 16]);
  float4 a0 = u0[0], a1 = u0[1], a2 = u0[2], a3 = u0[3];
  a0.x *= 0.5f; a0.y *= 0.5f; a0.z *= 0.5f; a0.w *= 0.5f;   // DC weight (imag dropped, pocketfft c2r)
  a1.x *= 0.5f; a1.y *= 0.5f; a1.z *= 0.5f; a1.w *= 0.5f;
  a2.x *= 0.5f; a2.y *= 0.5f; a2.z *= 0.5f; a2.w *= 0.5f;
  a3.x *= 0.5f; a3.y *= 0.5f; a3.z *= 0.5f; a3.w *= 0.5f;
  float cd, sd;
  sincosf((float)l * (TWO_PI_F / 1024.0f), &sd, &cd);
  float cc = cd, ss = sd;   // m = 1 twiddle
#pragma unroll 4
  for (int m = 1; m < 64; ++m) {
    const float4* ur = (const float4*)(&Us_r[m][og * 16]);
    const float4* ui = (const float4*)(&Us_i[m][og * 16]);
    float4 r0 = ur[0], r1 = ur[1], r2 = ur[2], r3 = ur[3];
    float4 i0 = ui[0], i1 = ui[1], i2 = ui[2], i3 = ui[3];
    RMAC4(a0, r0, i0)
    RMAC4(a1, r1, i1)
    RMAC4(a2, r2, i2)
    RMAC4(a3, r3, i3)
    float nc = cc * cd - ss * sd;
    ss = cc * sd + ss * cd;
    cc = nc;
  }
  const float SCALE = 7.4505805969238281e-9f;   // 2 / (1024 * 512 * 512) = 2^-27
  float* ob = out + ((size_t)bh * 64 + og * 16) * 1024 + l;
  ob[0 * 1024] = a0.x * SCALE;  ob[1 * 1024] = a0.y * SCALE;
  ob[2 * 1024] = a0.z * SCALE;  ob[3 * 1024] = a0.w * SCALE;
  ob[4 * 1024] = a1.x * SCALE;  ob[5 * 1024] = a1.y * SCALE;
  ob[6 * 1024] = a1.z * SCALE;  ob[7 * 1024] = a1.w * SCALE;
  ob[8 * 1024] = a2.x * SCALE;  ob[9 * 1024] = a2.y * SCALE;
  ob[10 * 1024] = a2.z * SCALE; ob[11 * 1024] = a2.w * SCALE;
  ob[12 * 1024] = a3.x * SCALE; ob[13 * 1024] = a3.y * SCALE;
  ob[14 * 1024] = a3.z * SCALE; ob[15 * 1024] = a3.w * SCALE;
}

extern "C" void kernel_launch(void* const* d_in, const int* in_sizes, int n_in,
                              void* d_out, int out_size, void* d_ws, size_t ws_size,
                              hipStream_t stream) {
  (void)in_sizes; (void)n_in; (void)out_size; (void)ws_size;
  const float* q  = (const float*)d_in[0];
  const float* k  = (const float*)d_in[1];
  // d_in[2] = v is unused by the reference
  const float* Wr = (const float*)d_in[3];
  const float* Wi = (const float*)d_in[4];
  float* out = (float*)d_out;
  float* ws  = (float*)d_ws;   // needs 48 MB

  hipLaunchKernelGGL(wtrans_kernel, dim3(512), dim3(256), 0, stream, Wr, Wi, ws);
  hipLaunchKernelGGL(dft_kernel,    dim3(512), dim3(256), 0, stream, q, k, ws);
  hipLaunchKernelGGL(qk_tanh_kernel,dim3(256), dim3(256), 0, stream, ws);
  hipLaunchKernelGGL(xqkv_kernel,   dim3(256), dim3(256), 0, stream, ws);
  hipLaunchKernelGGL(wmul_kernel,   dim3(512), dim3(256), 0, stream, ws);
  hipLaunchKernelGGL(idft_kernel,   dim3(4096), dim3(256), 0, stream, ws, out);
}

// Round 4
// 410.862 us; speedup vs baseline: 1.0266x; 1.0266x over previous
//
#include <hip/hip_runtime.h>
#include <math.h>

// FourierCrossAttention forward. B=32 L=1024 H=8 E=64 HE=512 M=64 O=64
// Precision strategy: the complex-tanh argument xqk is pole-sensitive
// (|Im| ~ 6e3, tanh poles at a=0, b=pi/2+k*pi; fp32 spectra give
// delta_b ~ 1e-3 -> realization-dependent 19%+ errors, round 2).
// Spectra + QK contraction in fp64; everything after tanh is smooth fp32.
// Round 4 fix: Wt is 2M floats = 8 MB per array (round 3 allocated 4 MB ->
// Wt/T overlap -> wmul used T-magnitude values as weights -> 3e5x errors).

#define TWO_PI_D 6.283185307179586476925286766559
#define TWO_PI_F 6.28318530717958647692f

// ---- workspace layout (BYTE offsets), total 48 MB ----
// Phase 1 (dft64):    writes XQ64 [0-16), XK64 [16-32)
// Phase 2 (qk_tanh):  reads  [0-32), writes T [32-40)
// Phase 3 (wtrans):   writes Wt [0-16)          (XQ64 dead)
// Phase 4 (xqkv):     reads XK64 [16-32), T [32-40); writes V [40-48)
// Phase 5 (wmul):     reads V [40-48), Wt [0-16); writes U [16-24)  (XK64 dead)
// Phase 6 (idft):     reads U [16-24); writes out
static constexpr size_t MB_ = 1024 * 1024;
static constexpr size_t XQ64R = 0;          // [B][M][HE] f64 (1M doubles = 8 MB)
static constexpr size_t XQ64I = 8 * MB_;
static constexpr size_t XK64R = 16 * MB_;
static constexpr size_t XK64I = 24 * MB_;
static constexpr size_t WTRb  = 0;          // [H][x][E][O] f32 (2M floats = 8 MB)
static constexpr size_t WTIb  = 8 * MB_;
static constexpr size_t TRb   = 32 * MB_;   // [B][H][Mq][Mkv] f32 (1M floats = 4 MB)
static constexpr size_t TIb   = 36 * MB_;
static constexpr size_t VRb   = 40 * MB_;   // [B][H][x][E] f32
static constexpr size_t VIb   = 44 * MB_;
static constexpr size_t URb   = 16 * MB_;   // [B][H][M][O] f32
static constexpr size_t UIb   = 20 * MB_;

__device__ __forceinline__ float f4c(const float4 v, int i) {
  return (i == 0) ? v.x : (i == 1) ? v.y : (i == 2) ? v.z : v.w;
}

// acc += (sr + i*si) * (br + i*bi), 4 lanes, fp32
__device__ __forceinline__ void cmac4(float4& ar, float4& ai, float sr, float si,
                                      const float4 br, const float4 bi) {
  ar.x += sr * br.x - si * bi.x;  ai.x += sr * bi.x + si * br.x;
  ar.y += sr * br.y - si * bi.y;  ai.y += sr * bi.y + si * br.y;
  ar.z += sr * br.z - si * bi.z;  ai.z += sr * bi.z + si * br.z;
  ar.w += sr * br.w - si * bi.w;  ai.w += sr * bi.w + si * br.w;
}

// ---------------- kernel T: W[h][e][o][x] -> Wt[h][x][e][o] -------------
// MUST run after qk_tanh (Wt overlays XQ64).
__global__ __launch_bounds__(256) void wtrans_kernel(const float* __restrict__ Wr,
                                                     const float* __restrict__ Wi,
                                                     char* __restrict__ wsb) {
  float* Wtr = (float*)(wsb + WTRb);
  float* Wti = (float*)(wsb + WTIb);
  const int h = blockIdx.x >> 6;
  const int tile = blockIdx.x & 63;   // tile = e
  const int t = threadIdx.x;
  __shared__ float lr[64][68], li_[64][68];
  const size_t rbase = (size_t)h * 262144 + (size_t)tile * 64 * 64;
#pragma unroll
  for (int i = 0; i < 4; ++i) {
    int idx = t + i * 256;
    int r = idx >> 4, x4 = idx & 15;
    float4 a = *(const float4*)(Wr + rbase + (size_t)r * 64 + x4 * 4);
    float4 b = *(const float4*)(Wi + rbase + (size_t)r * 64 + x4 * 4);
    *(float4*)(&lr[r][x4 * 4]) = a;
    *(float4*)(&li_[r][x4 * 4]) = b;
  }
  __syncthreads();
  const size_t wbase = (size_t)h * 262144 + (size_t)tile * 64;
#pragma unroll
  for (int i = 0; i < 4; ++i) {
    int idx = t + i * 256;
    int x = idx >> 4, r4 = idx & 15;
    float4 a, b;
    a.x = lr[r4 * 4 + 0][x]; a.y = lr[r4 * 4 + 1][x];
    a.z = lr[r4 * 4 + 2][x]; a.w = lr[r4 * 4 + 3][x];
    b.x = li_[r4 * 4 + 0][x]; b.y = li_[r4 * 4 + 1][x];
    b.z = li_[r4 * 4 + 2][x]; b.w = li_[r4 * 4 + 3][x];
    *(float4*)(Wtr + wbase + (size_t)x * 4096 + r4 * 4) = a;
    *(float4*)(Wti + wbase + (size_t)x * 4096 + r4 * 4) = b;
  }
}

// ---------------- kernel 1: fp64 64-mode DFT of q and k -----------------
// Real-input fold: X_m = x0 + (-1)^m x512
//                      + sum_{l=1}^{511} [s_l cos(th) - i d_l sin(th)]
//   s_l = x_l + x_{1024-l}, d_l = x_l - x_{1024-l} (exact in f64).
// grid 1024 = tz(2) x b(32) x het(16, 32-he tiles). block 128:
//   mt = t&31 (handles m=mt and m=mt+32), heg = t>>5 (8 he each).
__global__ __launch_bounds__(128) void dft64_kernel(const float* __restrict__ q,
                                                    const float* __restrict__ k,
                                                    char* __restrict__ wsb) {
  const int bi = blockIdx.x;
  const int tz = bi >> 9;
  const int b  = (bi >> 4) & 31;
  const int het = bi & 15;
  const float* src = tz ? k : q;
  double* dR = (double*)(wsb + (tz ? XK64R : XQ64R));
  double* dI = (double*)(wsb + (tz ? XK64I : XQ64I));
  const int t = threadIdx.x;
  const int mt = t & 31;
  const int heg = t >> 5;
  const int heL = heg * 8;
  const int heG = het * 32;

  __shared__ double sA[32][34], dA[32][34];   // pad 34 breaks write conflicts

  double re[2][8], im[2][8];
  const float* srcB = src + (size_t)b * 524288 + heG;
  // edge terms l=0, l=512 (sin=0; cos = 1 / (-1)^m; parity(mt)==parity(mt+32))
#pragma unroll
  for (int kk = 0; kk < 8; ++kk) {
    double x0 = (double)srcB[heL + kk];
    double x5 = (double)srcB[262144 + heL + kk];   // l=512 row
    double ev = (mt & 1) ? (x0 - x5) : (x0 + x5);
    re[0][kk] = ev; re[1][kk] = ev;
    im[0][kk] = 0.0; im[1][kk] = 0.0;
  }
  // f64 twiddles: seed at l=1, rotate by step; drift ~1e-13 over 512 steps
  double cc[2], ss[2], cd[2], sd[2];
#pragma unroll
  for (int mi = 0; mi < 2; ++mi) {
    double ang = (double)(mt + mi * 32) * (TWO_PI_D / 1024.0);
    sincos(ang, &sd[mi], &cd[mi]);
    cc[mi] = cd[mi]; ss[mi] = sd[mi];
  }
  const int jrow = t >> 2, part = t & 3;
  for (int c = 0; c < 16; ++c) {
    __syncthreads();
    {
      int l = c * 32 + jrow + 1;               // l in [1, 512]
      const float* fw = srcB + (size_t)l * 512 + part * 8;
      const float* mw = srcB + (size_t)(1024 - l) * 512 + part * 8;
      float4 f0 = *(const float4*)(fw);
      float4 f1 = *(const float4*)(fw + 4);
      float4 m0 = *(const float4*)(mw);
      float4 m1 = *(const float4*)(mw + 4);
      double fv[8] = {f0.x, f0.y, f0.z, f0.w, f1.x, f1.y, f1.z, f1.w};
      double mv[8] = {m0.x, m0.y, m0.z, m0.w, m1.x, m1.y, m1.z, m1.w};
      if (l == 512) {   // l=512 handled as edge term; zero this slot
#pragma unroll
        for (int kk = 0; kk < 8; ++kk) { fv[kk] = 0.0; mv[kk] = 0.0; }
      }
#pragma unroll
      for (int kk = 0; kk < 8; ++kk) {
        sA[jrow][part * 8 + kk] = fv[kk] + mv[kk];
        dA[jrow][part * 8 + kk] = fv[kk] - mv[kk];
      }
    }
    __syncthreads();
#pragma unroll 4
    for (int j = 0; j < 32; ++j) {
      double sv[8], dv[8];
#pragma unroll
      for (int kk = 0; kk < 8; ++kk) { sv[kk] = sA[j][heL + kk]; dv[kk] = dA[j][heL + kk]; }
#pragma unroll
      for (int mi = 0; mi < 2; ++mi) {
#pragma unroll
        for (int kk = 0; kk < 8; ++kk) {
          re[mi][kk] = fma(sv[kk], cc[mi], re[mi][kk]);
          im[mi][kk] = fma(-dv[kk], ss[mi], im[mi][kk]);
        }
        double nc = cc[mi] * cd[mi] - ss[mi] * sd[mi];
        ss[mi] = cc[mi] * sd[mi] + ss[mi] * cd[mi];
        cc[mi] = nc;
      }
    }
  }
#pragma unroll
  for (int mi = 0; mi < 2; ++mi) {
    int m = mt + mi * 32;
    double* oR = dR + (size_t)b * 32768 + (size_t)m * 512 + heG + heL;
    double* oI = dI + (size_t)b * 32768 + (size_t)m * 512 + heG + heL;
#pragma unroll
    for (int kk = 0; kk < 8; ++kk) { oR[kk] = re[mi][kk]; oI[kk] = im[mi][kk]; }
  }
}

// ---------------- complex tanh from f64 argument ------------------------
// tanh(a+ib) = (sinh2a + i sin2b) / (cosh2a + cos2b).
// Range-reduce 2b mod 2pi in f64, then evaluate transcendentals in f32.
__device__ __forceinline__ void ctanh_d(double a, double b, float& re, float& im) {
  double aa = fabs(a);
  if (aa > 12.0) {                 // cosh(24)=2.6e10: im ~ 1e-10, re saturates
    re = (a >= 0.0) ? 1.0f : -1.0f;
    im = 0.0f;
    return;
  }
  float e2 = __expf((float)(2.0 * aa));
  float ie = 1.0f / e2;
  float sh = 0.5f * (e2 - ie);
  float ch = 0.5f * (e2 + ie);
  double phi = 2.0 * b;
  double n = rint(phi * (1.0 / TWO_PI_D));
  float r = (float)fma(-n, TWO_PI_D, phi);   // in [-pi, pi]
  float s2, c2;
  sincosf(r, &s2, &c2);
  float d = ch + c2;
  float id = 1.0f / d;
  re = ((a >= 0.0) ? sh : -sh) * id;
  im = s2 * id;
}

// ---------------- kernel 2: T = tanh(XQ64 . XK64^T over e), f64 ---------
// grid 256 (b,h). block 256 = 16 tx x 16 ty; thread owns 4x * 4y outputs.
__global__ __launch_bounds__(256) void qk_tanh_kernel(char* __restrict__ wsb) {
  const double* Qr = (const double*)(wsb + XQ64R);
  const double* Qi = (const double*)(wsb + XQ64I);
  const double* Kr = (const double*)(wsb + XK64R);
  const double* Ki = (const double*)(wsb + XK64I);
  float* Trp = (float*)(wsb + TRb);
  float* Tip = (float*)(wsb + TIb);
  const int bh = blockIdx.x;
  const int b = bh >> 3, h = bh & 7;
  const int t = threadIdx.x;
  const int tx = t & 15, ty = t >> 4;
  __shared__ double Qsr[16][66], Qsi[16][66], Ksr[16][66], Ksi[16][66];  // 33.8 KB
  double are[4][4] = {}, aim[4][4] = {};
  const int row = t >> 2, ep = t & 3;   // loader mapping
  for (int ec = 0; ec < 4; ++ec) {
    __syncthreads();
    {
      size_t g = (size_t)b * 32768 + (size_t)row * 512 + h * 64 + ec * 16 + ep * 4;
      double2 a0, a1;
      a0 = *(const double2*)(Qr + g); a1 = *(const double2*)(Qr + g + 2);
      Qsr[ep*4+0][row] = a0.x; Qsr[ep*4+1][row] = a0.y;
      Qsr[ep*4+2][row] = a1.x; Qsr[ep*4+3][row] = a1.y;
      a0 = *(const double2*)(Qi + g); a1 = *(const double2*)(Qi + g + 2);
      Qsi[ep*4+0][row] = a0.x; Qsi[ep*4+1][row] = a0.y;
      Qsi[ep*4+2][row] = a1.x; Qsi[ep*4+3][row] = a1.y;
      a0 = *(const double2*)(Kr + g); a1 = *(const double2*)(Kr + g + 2);
      Ksr[ep*4+0][row] = a0.x; Ksr[ep*4+1][row] = a0.y;
      Ksr[ep*4+2][row] = a1.x; Ksr[ep*4+3][row] = a1.y;
      a0 = *(const double2*)(Ki + g); a1 = *(const double2*)(Ki + g + 2);
      Ksi[ep*4+0][row] = a0.x; Ksi[ep*4+1][row] = a0.y;
      Ksi[ep*4+2][row] = a1.x; Ksi[ep*4+3][row] = a1.y;
    }
    __syncthreads();
#pragma unroll 4
    for (int el = 0; el < 16; ++el) {
      double qr[4], qi2[4], kr[4], ki2[4];
#pragma unroll
      for (int u = 0; u < 4; ++u) {
        qr[u]  = Qsr[el][tx * 4 + u];
        qi2[u] = Qsi[el][tx * 4 + u];
        kr[u]  = Ksr[el][ty * 4 + u];
        ki2[u] = Ksi[el][ty * 4 + u];
      }
#pragma unroll
      for (int xx = 0; xx < 4; ++xx)
#pragma unroll
        for (int yy = 0; yy < 4; ++yy) {
          are[xx][yy] = fma(qr[xx], kr[yy], fma(-qi2[xx], ki2[yy], are[xx][yy]));
          aim[xx][yy] = fma(qr[xx], ki2[yy], fma(qi2[xx], kr[yy], aim[xx][yy]));
        }
    }
  }
#pragma unroll
  for (int xx = 0; xx < 4; ++xx) {
    int x = tx * 4 + xx;
    float4 tR, tI;
    ctanh_d(are[xx][0], aim[xx][0], tR.x, tI.x);
    ctanh_d(are[xx][1], aim[xx][1], tR.y, tI.y);
    ctanh_d(are[xx][2], aim[xx][2], tR.z, tI.z);
    ctanh_d(are[xx][3], aim[xx][3], tR.w, tI.w);
    *(float4*)(Trp + ((size_t)bh * 64 + x) * 64 + ty * 4) = tR;
    *(float4*)(Tip + ((size_t)bh * 64 + x) * 64 + ty * 4) = tI;
  }
}

// ---------------- kernel 3: V[x][e] = sum_y T[x][y] * XK[y][e] ----------
// grid 1024 (b,h,xt). thread: x = xt*16 + (t>>4), eg = t&15 (4 e each).
__global__ __launch_bounds__(256) void xqkv_kernel(char* __restrict__ wsb) {
  const double* XKr64 = (const double*)(wsb + XK64R);
  const double* XKi64 = (const double*)(wsb + XK64I);
  const float* Trp = (const float*)(wsb + TRb);
  const float* Tip = (const float*)(wsb + TIb);
  float* Vr = (float*)(wsb + VRb);
  float* Vi = (float*)(wsb + VIb);
  const int bh = blockIdx.x >> 2;
  const int xt = blockIdx.x & 3;
  const int b = bh >> 3, h = bh & 7;
  const int t = threadIdx.x;
  const int x = xt * 16 + (t >> 4);
  const int eg = t & 15;
  __shared__ float Kr[64][64], Ki[64][64];   // [y][e]
#pragma unroll
  for (int i = 0; i < 4; ++i) {
    int idx = t + i * 256;
    int yl = idx >> 4, e4 = idx & 15;
    size_t g = (size_t)b * 32768 + (size_t)yl * 512 + h * 64 + e4 * 4;
    double2 r0 = *(const double2*)(XKr64 + g);
    double2 r1 = *(const double2*)(XKr64 + g + 2);
    double2 i0 = *(const double2*)(XKi64 + g);
    double2 i1 = *(const double2*)(XKi64 + g + 2);
    *(float4*)(&Kr[yl][e4 * 4]) = make_float4((float)r0.x, (float)r0.y, (float)r1.x, (float)r1.y);
    *(float4*)(&Ki[yl][e4 * 4]) = make_float4((float)i0.x, (float)i0.y, (float)i1.x, (float)i1.y);
  }
  __syncthreads();
  float4 aR = {0,0,0,0}, aI = {0,0,0,0};
  const float* tbr = Trp + ((size_t)bh * 64 + x) * 64;
  const float* tbi = Tip + ((size_t)bh * 64 + x) * 64;
  for (int yc = 0; yc < 4; ++yc) {
    float4 pr[4], pim[4];
    const float4* gr = (const float4*)(tbr + yc * 16);
    const float4* gi = (const float4*)(tbi + yc * 16);
    pr[0] = gr[0]; pr[1] = gr[1]; pr[2] = gr[2]; pr[3] = gr[3];
    pim[0] = gi[0]; pim[1] = gi[1]; pim[2] = gi[2]; pim[3] = gi[3];
#pragma unroll
    for (int jj = 0; jj < 16; ++jj) {
      int y = yc * 16 + jj;
      float sr = f4c(pr[jj >> 2], jj & 3);
      float si = f4c(pim[jj >> 2], jj & 3);
      const float4 br = *(const float4*)(&Kr[y][eg * 4]);
      const float4 bi = *(const float4*)(&Ki[y][eg * 4]);
      cmac4(aR, aI, sr, si, br, bi);
    }
  }
  float* oR = Vr + ((size_t)bh * 64 + x) * 64 + eg * 4;
  float* oI = Vi + ((size_t)bh * 64 + x) * 64 + eg * 4;
  *(float4*)oR = aR;
  *(float4*)oI = aI;
}

// ---------------- kernel 4: U[b,h,x,o] = sum_e V[b,h,x,e]*Wt[h,x,e,o] ---
// grid 1024 (h,x,bt). thread: bI = bt*16 + (t>>4), og = t&15 (4 o each).
__global__ __launch_bounds__(256) void wmul_kernel(char* __restrict__ wsb) {
  const float* Vr = (const float*)(wsb + VRb);
  const float* Vi = (const float*)(wsb + VIb);
  float* Ur = (float*)(wsb + URb);
  float* Ui = (float*)(wsb + UIb);
  const float* Wtr = (const float*)(wsb + WTRb);
  const float* Wti = (const float*)(wsb + WTIb);
  const int h = blockIdx.x >> 7;
  const int x = (blockIdx.x >> 1) & 63;
  const int bt = blockIdx.x & 1;
  const int t = threadIdx.x;
  const int bI = bt * 16 + (t >> 4);
  const int og = t & 15;
  __shared__ float Ws_r[64][64], Ws_i[64][64];   // [e][o]
  const size_t wb = ((size_t)h * 64 + x) * 4096;
#pragma unroll
  for (int i = 0; i < 4; ++i) {
    int idx = t + i * 256;
    int el = idx >> 4, o4 = idx & 15;
    *(float4*)(&Ws_r[el][o4 * 4]) = *(const float4*)(Wtr + wb + (size_t)el * 64 + o4 * 4);
    *(float4*)(&Ws_i[el][o4 * 4]) = *(const float4*)(Wti + wb + (size_t)el * 64 + o4 * 4);
  }
  __syncthreads();
  float4 aR = {0,0,0,0}, aI = {0,0,0,0};
  const float* vbr = Vr + (((size_t)bI * 8 + h) * 64 + x) * 64;
  const float* vbi = Vi + (((size_t)bI * 8 + h) * 64 + x) * 64;
  for (int ec = 0; ec < 4; ++ec) {
    float4 pr[4], pim[4];
    const float4* gr = (const float4*)(vbr + ec * 16);
    const float4* gi = (const float4*)(vbi + ec * 16);
    pr[0] = gr[0]; pr[1] = gr[1]; pr[2] = gr[2]; pr[3] = gr[3];
    pim[0] = gi[0]; pim[1] = gi[1]; pim[2] = gi[2]; pim[3] = gi[3];
#pragma unroll
    for (int jj = 0; jj < 16; ++jj) {
      int e = ec * 16 + jj;
      float sr = f4c(pr[jj >> 2], jj & 3);
      float si = f4c(pim[jj >> 2], jj & 3);
      const float4 br = *(const float4*)(&Ws_r[e][og * 4]);
      const float4 bi = *(const float4*)(&Ws_i[e][og * 4]);
      cmac4(aR, aI, sr, si, br, bi);
    }
  }
  float* oR = Ur + (((size_t)bI * 8 + h) * 64 + x) * 64 + og * 4;
  float* oI = Ui + (((size_t)bI * 8 + h) * 64 + x) * 64 + og * 4;
  *(float4*)oR = aR;
  *(float4*)oI = aI;
}

// ---------------- kernel 5: irfft (64 modes -> 1024), 4 l per thread ----
// grid 1024 = (b,h)*4 l-tiles. thread: l = lt*64 + (t&63) (+256k), og = t>>6.
// twiddle for l+256k = i^(m*k) * twiddle(l), folded statically by unroll.
__global__ __launch_bounds__(256) void idft_kernel(const char* __restrict__ wsb,
                                                   float* __restrict__ out) {
  const float* Ur = (const float*)(wsb + URb);
  const float* Ui = (const float*)(wsb + UIb);
  const int bh = blockIdx.x >> 2;
  const int lt = blockIdx.x & 3;
  const int t = threadIdx.x;
  const int l = lt * 64 + (t & 63);
  const int og = t >> 6;
  __shared__ float Us_r[64][64], Us_i[64][64];   // [m][o]
#pragma unroll
  for (int i = 0; i < 4; ++i) {
    int idx = t + i * 256;
    int ml = idx >> 4, o4 = idx & 15;
    size_t g = ((size_t)bh * 64 + ml) * 64 + o4 * 4;
    *(float4*)(&Us_r[ml][o4 * 4]) = *(const float4*)(Ur + g);
    *(float4*)(&Us_i[ml][o4 * 4]) = *(const float4*)(Ui + g);
  }
  __syncthreads();
  float4 a[4][4];
  const float4* u0 = (const float4*)(&Us_r[0][og * 16]);
#pragma unroll
  for (int j = 0; j < 4; ++j) {
    float4 v = u0[j];
    v.x *= 0.5f; v.y *= 0.5f; v.z *= 0.5f; v.w *= 0.5f;   // DC weight (imag dropped)
    a[0][j] = v; a[1][j] = v; a[2][j] = v; a[3][j] = v;
  }
  float cd, sd;
  sincosf((float)l * (TWO_PI_F / 1024.0f), &sd, &cd);
  float cc = cd, ss = sd;   // m = 1 twiddle
#pragma unroll 4
  for (int m = 1; m < 64; ++m) {
    const float4* ur = (const float4*)(&Us_r[m][og * 16]);
    const float4* ui = (const float4*)(&Us_i[m][og * 16]);
    float4 R[4], I[4];
#pragma unroll
    for (int j = 0; j < 4; ++j) { R[j] = ur[j]; I[j] = ui[j]; }
#pragma unroll
    for (int k = 0; k < 4; ++k) {
      int rot = (m * k) & 3;
      float cP = (rot == 0) ? cc : (rot == 1) ? -ss : (rot == 2) ? -cc : ss;
      float sP = (rot == 0) ? ss : (rot == 1) ? cc : (rot == 2) ? -ss : -cc;
#pragma unroll
      for (int j = 0; j < 4; ++j) {
        a[k][j].x += cP * R[j].x - sP * I[j].x;
        a[k][j].y += cP * R[j].y - sP * I[j].y;
        a[k][j].z += cP * R[j].z - sP * I[j].z;
        a[k][j].w += cP * R[j].w - sP * I[j].w;
      }
    }
    float nc = cc * cd - ss * sd;
    ss = cc * sd + ss * cd;
    cc = nc;
  }
  const float SCALE = 7.4505805969238281e-9f;   // 2 / (1024 * 512 * 512)
  float* obase = out + ((size_t)bh * 64 + og * 16) * 1024 + l;
#pragma unroll
  for (int k = 0; k < 4; ++k) {
    float* ob = obase + 256 * k;
#pragma unroll
    for (int r = 0; r < 16; ++r) {
      ob[(size_t)r * 1024] = f4c(a[k][r >> 2], r & 3) * SCALE;
    }
  }
}

extern "C" void kernel_launch(void* const* d_in, const int* in_sizes, int n_in,
                              void* d_out, int out_size, void* d_ws, size_t ws_size,
                              hipStream_t stream) {
  (void)in_sizes; (void)n_in; (void)out_size; (void)ws_size;
  const float* q  = (const float*)d_in[0];
  const float* k  = (const float*)d_in[1];
  // d_in[2] = v is unused by the reference
  const float* Wr = (const float*)d_in[3];
  const float* Wi = (const float*)d_in[4];
  float* out = (float*)d_out;
  char* wsb  = (char*)d_ws;   // needs 48 MB

  hipLaunchKernelGGL(dft64_kernel,   dim3(1024), dim3(128), 0, stream, q, k, wsb);
  hipLaunchKernelGGL(qk_tanh_kernel, dim3(256),  dim3(256), 0, stream, wsb);
  hipLaunchKernelGGL(wtrans_kernel,  dim3(512),  dim3(256), 0, stream, Wr, Wi, wsb);  // after qk: Wt overlays XQ64
  hipLaunchKernelGGL(xqkv_kernel,    dim3(1024), dim3(256), 0, stream, wsb);
  hipLaunchKernelGGL(wmul_kernel,    dim3(1024), dim3(256), 0, stream, wsb);
  hipLaunchKernelGGL(idft_kernel,    dim3(1024), dim3(256), 0, stream, wsb, out);
}